// Round 3
// baseline (5686.484 us; speedup 1.0000x reference)
//
#include <hip/hip_runtime.h>
#include <hip/hip_bf16.h>

#define T_STEPS 2048
#define HDIM 256
#define VOUT 32000

typedef short short8 __attribute__((ext_vector_type(8)));
typedef float f32x4 __attribute__((ext_vector_type(4)));

// ---------- int8 dot4 (signed) with fallback ----------
#if defined(__has_builtin)
#if __has_builtin(__builtin_amdgcn_sdot4)
#define HAVE_SDOT4 1
#endif
#endif

__device__ __forceinline__ int dot4i8(int a, int b, int c) {
#ifdef HAVE_SDOT4
    return __builtin_amdgcn_sdot4(a, b, c, false);
#else
#pragma unroll
    for (int k = 0; k < 4; ++k) {
        int av = (a << (24 - 8 * k)) >> 24;
        int bv = (b << (24 - 8 * k)) >> 24;
        c += av * bv;
    }
    return c;
#endif
}

__device__ __forceinline__ float fast_sigmoid(float x) {
    return 1.0f / (1.0f + __expf(-x));
}
__device__ __forceinline__ float fast_tanh(float x) {
    float ax = fabsf(x);
    float e = __expf(-2.0f * ax);
    float t = 1.0f - 2.0f * e / (1.0f + e);
    return copysignf(t, x);
}

// ---------- quantize a 768x256 fp32 matrix to int8 (per-row scale) ----------
__global__ void k_quant(const float* __restrict__ W, int* __restrict__ wq,
                        float* __restrict__ sc) {
    int row = blockIdx.x;
    int t = threadIdx.x;
    float4 w = ((const float4*)(W + (size_t)row * HDIM))[t];
    float m = fmaxf(fmaxf(fabsf(w.x), fabsf(w.y)), fmaxf(fabsf(w.z), fabsf(w.w)));
#pragma unroll
    for (int off = 32; off; off >>= 1) m = fmaxf(m, __shfl_xor(m, off));
    float inv = (m > 0.0f) ? 127.0f / m : 0.0f;
    float scale = (m > 0.0f) ? m * (1.0f / 127.0f) : 0.0f;
    int q0 = __float2int_rn(w.x * inv); q0 = max(-127, min(127, q0));
    int q1 = __float2int_rn(w.y * inv); q1 = max(-127, min(127, q1));
    int q2 = __float2int_rn(w.z * inv); q2 = max(-127, min(127, q2));
    int q3 = __float2int_rn(w.w * inv); q3 = max(-127, min(127, q3));
    int packed = (q0 & 255) | ((q1 & 255) << 8) | ((q2 & 255) << 16) | ((q3 & 255) << 24);
    wq[row * 64 + t] = packed;
    if (t == 0) sc[row] = scale;
}

// ---------- fp32 -> bf16 (RNE) ----------
__global__ __launch_bounds__(256) void k_cvt(const float* __restrict__ in,
                                             unsigned short* __restrict__ out, int n4) {
    int i = blockIdx.x * 256 + threadIdx.x;
    if (i < n4) {
        float4 v = ((const float4*)in)[i];
        unsigned int u[4] = {__float_as_uint(v.x), __float_as_uint(v.y),
                             __float_as_uint(v.z), __float_as_uint(v.w)};
        ushort4 o;
        o.x = (unsigned short)((u[0] + 0x7FFFu + ((u[0] >> 16) & 1)) >> 16);
        o.y = (unsigned short)((u[1] + 0x7FFFu + ((u[1] >> 16) & 1)) >> 16);
        o.z = (unsigned short)((u[2] + 0x7FFFu + ((u[2] >> 16) & 1)) >> 16);
        o.w = (unsigned short)((u[3] + 0x7FFFu + ((u[3] >> 16) & 1)) >> 16);
        ((ushort4*)out)[i] = o;
    }
}

// ---------- Phase A: gi[t][row] = W_ih @ x_t + b_ih ----------
__global__ __launch_bounds__(256) void k_gi(const int* __restrict__ toks,
                                            const float* __restrict__ emb,
                                            const float* __restrict__ W,
                                            const float* __restrict__ b,
                                            float* __restrict__ gi, int do_relu) {
    __shared__ float4 xs[64];
    int t = blockIdx.x;
    int tid = threadIdx.x;
    int tok = toks[t];
    if (tid < 64) {
        float4 x = ((const float4*)(emb + (size_t)tok * HDIM))[tid];
        if (do_relu) {
            x.x = fmaxf(x.x, 0.0f); x.y = fmaxf(x.y, 0.0f);
            x.z = fmaxf(x.z, 0.0f); x.w = fmaxf(x.w, 0.0f);
        }
        xs[tid] = x;
    }
    __syncthreads();
#pragma unroll
    for (int g = 0; g < 3; ++g) {
        int row = tid + g * 256;
        const float4* wr = (const float4*)(W + (size_t)row * HDIM);
        float acc = b[row];
#pragma unroll 16
        for (int k = 0; k < 64; ++k) {
            float4 w = wr[k];
            float4 x = xs[k];
            acc += w.x * x.x + w.y * x.y + w.z * x.z + w.w * x.w;
        }
        gi[(size_t)t * 768 + row] = acc;
    }
}

// ---------- Phase B: sequential double-GRU, one workgroup of 256 threads ----------
// Thread i owns rows {i, 256+i, 512+i} of BOTH W_hh matrices fully in registers
// (384 VGPRs of weights; 1 wave/SIMD so up to 512 available). After its 3 dots it
// computes r,z,n,h LOCALLY -> no gate wave, no Y tile. h shared via a
// double-buffered 256-byte HQ (int8) -> exactly ONE barrier per half-step.
// gi loads prefetched one step ahead to hide HBM latency.
__global__ __launch_bounds__(256, 1) void k_gru(
    const int* __restrict__ wq_e, const float* __restrict__ sc_e,
    const float* __restrict__ bhh_e, const float* __restrict__ gi_e,
    const int* __restrict__ wq_d, const float* __restrict__ sc_d,
    const float* __restrict__ bhh_d, const float* __restrict__ gi_d,
    float* __restrict__ h_all) {
    __shared__ __align__(16) int HQ0[64];  // h entering encoder (post-decoder)
    __shared__ __align__(16) int HQ1[64];  // h entering decoder (post-encoder)

    const int i = threadIdx.x;

    // ---- load weights: rows i, 256+i, 512+i of both matrices ----
    int we[3][64], wd[3][64];
#pragma unroll
    for (int j = 0; j < 3; ++j) {
        const int4* pe = (const int4*)(wq_e + (j * 256 + i) * 64);
        const int4* pd = (const int4*)(wq_d + (j * 256 + i) * 64);
#pragma unroll
        for (int q = 0; q < 16; ++q) {
            int4 a = pe[q];
            we[j][4 * q + 0] = a.x; we[j][4 * q + 1] = a.y;
            we[j][4 * q + 2] = a.z; we[j][4 * q + 3] = a.w;
            int4 bq = pd[q];
            wd[j][4 * q + 0] = bq.x; wd[j][4 * q + 1] = bq.y;
            wd[j][4 * q + 2] = bq.z; wd[j][4 * q + 3] = bq.w;
        }
    }
    const float ser = sc_e[i] * (1.0f / 127.0f);
    const float sez = sc_e[256 + i] * (1.0f / 127.0f);
    const float sen = sc_e[512 + i] * (1.0f / 127.0f);
    const float sdr = sc_d[i] * (1.0f / 127.0f);
    const float sdz = sc_d[256 + i] * (1.0f / 127.0f);
    const float sdn = sc_d[512 + i] * (1.0f / 127.0f);
    const float ber = bhh_e[i];
    const float bez = bhh_e[256 + i];
    const float ben = bhh_e[512 + i];
    const float bdr = bhh_d[i];
    const float bdz = bhh_d[256 + i];
    const float bdn = bhh_d[512 + i];

    float h = 0.0f;
    if (i < 64) HQ0[i] = 0;

    // prefetch gi for t=0
    const float* pge = gi_e + i;
    const float* pgd = gi_d + i;
    float ger = pge[0], gez = pge[256], gen = pge[512];
    float gdr = pgd[0], gdz = pgd[256], gdn = pgd[512];
    pge += 768; pgd += 768;
    float* hop = h_all + i;

    __syncthreads();

    for (int t = 0; t < T_STEPS; ++t) {
        // prefetch gi for t+1 (reads 768-float pad after array at t=2047; unused)
        float n_ger = pge[0], n_gez = pge[256], n_gen = pge[512];
        float n_gdr = pgd[0], n_gdz = pgd[256], n_gdn = pgd[512];
        pge += 768; pgd += 768;

        // ---- encoder half: read HQ0, write HQ1 ----
        {
            int pr = 0, pz = 0, pn = 0;
            const int4* hq = (const int4*)HQ0;
#pragma unroll
            for (int q = 0; q < 16; ++q) {
                int4 a = hq[q];  // same address in all lanes: broadcast
                pr = dot4i8(we[0][4 * q + 0], a.x, pr);
                pr = dot4i8(we[0][4 * q + 1], a.y, pr);
                pr = dot4i8(we[0][4 * q + 2], a.z, pr);
                pr = dot4i8(we[0][4 * q + 3], a.w, pr);
                pz = dot4i8(we[1][4 * q + 0], a.x, pz);
                pz = dot4i8(we[1][4 * q + 1], a.y, pz);
                pz = dot4i8(we[1][4 * q + 2], a.z, pz);
                pz = dot4i8(we[1][4 * q + 3], a.w, pz);
                pn = dot4i8(we[2][4 * q + 0], a.x, pn);
                pn = dot4i8(we[2][4 * q + 1], a.y, pn);
                pn = dot4i8(we[2][4 * q + 2], a.z, pn);
                pn = dot4i8(we[2][4 * q + 3], a.w, pn);
            }
            float r = fast_sigmoid(ser * (float)pr + ber + ger);
            float z = fast_sigmoid(sez * (float)pz + bez + gez);
            float n = fast_tanh(gen + r * (sen * (float)pn + ben));
            h = (1.0f - z) * n + z * h;
            ((signed char*)HQ1)[i] = (signed char)__float2int_rn(h * 127.0f);
        }
        __syncthreads();

        // ---- decoder half: read HQ1, write HQ0 ----
        {
            int pr = 0, pz = 0, pn = 0;
            const int4* hq = (const int4*)HQ1;
#pragma unroll
            for (int q = 0; q < 16; ++q) {
                int4 a = hq[q];
                pr = dot4i8(wd[0][4 * q + 0], a.x, pr);
                pr = dot4i8(wd[0][4 * q + 1], a.y, pr);
                pr = dot4i8(wd[0][4 * q + 2], a.z, pr);
                pr = dot4i8(wd[0][4 * q + 3], a.w, pr);
                pz = dot4i8(wd[1][4 * q + 0], a.x, pz);
                pz = dot4i8(wd[1][4 * q + 1], a.y, pz);
                pz = dot4i8(wd[1][4 * q + 2], a.z, pz);
                pz = dot4i8(wd[1][4 * q + 3], a.w, pz);
                pn = dot4i8(wd[2][4 * q + 0], a.x, pn);
                pn = dot4i8(wd[2][4 * q + 1], a.y, pn);
                pn = dot4i8(wd[2][4 * q + 2], a.z, pn);
                pn = dot4i8(wd[2][4 * q + 3], a.w, pn);
            }
            float r = fast_sigmoid(sdr * (float)pr + bdr + gdr);
            float z = fast_sigmoid(sdz * (float)pz + bdz + gdz);
            float n = fast_tanh(gdn + r * (sdn * (float)pn + bdn));
            h = (1.0f - z) * n + z * h;
            *hop = h; hop += 256;
            ((signed char*)HQ0)[i] = (signed char)__float2int_rn(h * 127.0f);
        }
        __syncthreads();

        ger = n_ger; gez = n_gez; gen = n_gen;
        gdr = n_gdr; gdz = n_gdz; gdn = n_gdn;
    }
}

// ---------- Phase C1: logits = H(2048x256) @ out_W^T + b via bf16 MFMA ----------
// Grid: x = t-tile (32), y = v-tile (500). Consecutive blocks share the same
// B-tile (32 KB, L2/L1-hot); the re-read A matrix is only 1 MB (L2-resident).
__global__ __launch_bounds__(256) void k_logits(const unsigned short* __restrict__ hb,
                                                const unsigned short* __restrict__ wb,
                                                const float* __restrict__ out_b,
                                                float* __restrict__ out) {
    const int tb = blockIdx.x * 64;
    const int vb = blockIdx.y * 64;
    const int w = threadIdx.x >> 6;
    const int l = threadIdx.x & 63;
    const int m = l & 15;
    const int q = l >> 4;

    const unsigned short* aptr = hb + (size_t)(tb + w * 16 + m) * HDIM + q * 8;
    const unsigned short* bptr = wb + (size_t)(vb + m) * HDIM + q * 8;

    short8 af[8];
#pragma unroll
    for (int kt = 0; kt < 8; ++kt) af[kt] = *(const short8*)(aptr + kt * 32);

    f32x4 acc[4];
#pragma unroll
    for (int nt = 0; nt < 4; ++nt)
#pragma unroll
        for (int r = 0; r < 4; ++r) acc[nt][r] = 0.0f;

#pragma unroll
    for (int nt = 0; nt < 4; ++nt) {
        const unsigned short* bp = bptr + (size_t)nt * 16 * HDIM;
#pragma unroll
        for (int kt = 0; kt < 8; ++kt) {
            short8 bf = *(const short8*)(bp + kt * 32);
            acc[nt] = __builtin_amdgcn_mfma_f32_16x16x32_bf16(af[kt], bf, acc[nt], 0, 0, 0);
        }
    }
#pragma unroll
    for (int nt = 0; nt < 4; ++nt) {
        float bias = out_b[vb + nt * 16 + m];
#pragma unroll
        for (int r = 0; r < 4; ++r) {
            out[(size_t)(tb + w * 16 + q * 4 + r) * VOUT + vb + nt * 16 + m] =
                acc[nt][r] + bias;
        }
    }
}

// ---------- Phase C2: per-row logsumexp ----------
__global__ __launch_bounds__(256) void k_lse(const float* __restrict__ out,
                                             float* __restrict__ lse) {
    const int t = blockIdx.x;
    const int tid = threadIdx.x;
    const float* rowp = out + (size_t)t * VOUT;
    float m = -3.0e38f, l = 0.0f;
    for (int v = tid; v < VOUT; v += 256) {
        float x = rowp[v];
        float M = fmaxf(m, x);
        l = l * __expf(m - M) + __expf(x - M);
        m = M;
    }
#pragma unroll
    for (int off = 32; off; off >>= 1) {
        float m2 = __shfl_xor(m, off);
        float l2 = __shfl_xor(l, off);
        float M = fmaxf(m, m2);
        l = l * __expf(m - M) + l2 * __expf(m2 - M);
        m = M;
    }
    __shared__ float sm[4], sl[4];
    int lane = tid & 63, wv = tid >> 6;
    if (lane == 0) { sm[wv] = m; sl[wv] = l; }
    __syncthreads();
    if (tid == 0) {
        float M = fmaxf(fmaxf(sm[0], sm[1]), fmaxf(sm[2], sm[3]));
        float L = sl[0] * __expf(sm[0] - M) + sl[1] * __expf(sm[1] - M) +
                  sl[2] * __expf(sm[2] - M) + sl[3] * __expf(sm[3] - M);
        lse[t] = M + __logf(L);
    }
}

// ---------- Phase C3: out -= lse[t] ----------
__global__ __launch_bounds__(256) void k_sub(float* __restrict__ out,
                                             const float* __restrict__ lse) {
    const int t = blockIdx.y;
    const int v4 = blockIdx.x * 256 + threadIdx.x;
    if (v4 < VOUT / 4) {
        float s = lse[t];
        float4* p = (float4*)(out + (size_t)t * VOUT) + v4;
        float4 o = *p;
        o.x -= s; o.y -= s; o.z -= s; o.w -= s;
        *p = o;
    }
}

extern "C" void kernel_launch(void* const* d_in, const int* in_sizes, int n_in,
                              void* d_out, int out_size, void* d_ws, size_t ws_size,
                              hipStream_t stream) {
    (void)in_sizes; (void)n_in; (void)out_size; (void)ws_size;
    const int*   src      = (const int*)d_in[0];
    const int*   trg      = (const int*)d_in[1];
    const float* enc_emb  = (const float*)d_in[2];
    const float* enc_W_ih = (const float*)d_in[3];
    const float* enc_W_hh = (const float*)d_in[4];
    const float* enc_b_ih = (const float*)d_in[5];
    const float* enc_b_hh = (const float*)d_in[6];
    const float* dec_emb  = (const float*)d_in[7];
    const float* dec_W_ih = (const float*)d_in[8];
    const float* dec_W_hh = (const float*)d_in[9];
    const float* dec_b_ih = (const float*)d_in[10];
    const float* dec_b_hh = (const float*)d_in[11];
    const float* out_W    = (const float*)d_in[12];
    const float* out_b    = (const float*)d_in[13];
    float* out = (float*)d_out;

    char* ws = (char*)d_ws;
    // gi arrays get one extra 768-float step of pad (prefetch overshoot at t=2047)
    float* gi_e  = (float*)ws; ws += (size_t)(T_STEPS + 1) * 768 * 4;
    float* gi_d  = (float*)ws; ws += (size_t)(T_STEPS + 1) * 768 * 4;
    float* h_all = (float*)ws; ws += (size_t)T_STEPS * HDIM * 4;
    float* lse   = (float*)ws; ws += (size_t)T_STEPS * 4;
    float* sc_e  = (float*)ws; ws += 768 * 4;
    float* sc_d  = (float*)ws; ws += 768 * 4;
    int*   wq_e  = (int*)ws;   ws += 768 * 64 * 4;
    int*   wq_d  = (int*)ws;   ws += 768 * 64 * 4;
    unsigned short* h_bf = (unsigned short*)ws; ws += (size_t)T_STEPS * HDIM * 2;
    unsigned short* w_bf = (unsigned short*)ws; ws += (size_t)VOUT * HDIM * 2;

    k_quant<<<768, 64, 0, stream>>>(enc_W_hh, wq_e, sc_e);
    k_quant<<<768, 64, 0, stream>>>(dec_W_hh, wq_d, sc_d);
    k_cvt<<<(VOUT * HDIM / 4 + 255) / 256, 256, 0, stream>>>(out_W, w_bf, VOUT * HDIM / 4);
    k_gi<<<T_STEPS, 256, 0, stream>>>(src, enc_emb, enc_W_ih, enc_b_ih, gi_e, 0);
    k_gi<<<T_STEPS, 256, 0, stream>>>(trg, dec_emb, dec_W_ih, dec_b_ih, gi_d, 1);
    k_gru<<<1, 256, 0, stream>>>(wq_e, sc_e, enc_b_hh, gi_e,
                                 wq_d, sc_d, dec_b_hh, gi_d, h_all);
    k_cvt<<<(T_STEPS * HDIM / 4 + 255) / 256, 256, 0, stream>>>(h_all, h_bf, T_STEPS * HDIM / 4);
    k_logits<<<dim3(T_STEPS / 64, VOUT / 64), 256, 0, stream>>>(h_bf, w_bf, out_b, out);
    k_lse<<<T_STEPS, 256, 0, stream>>>(out, lse);
    k_sub<<<dim3(32, T_STEPS), 256, 0, stream>>>(out, lse);
}